// Round 1
// baseline (3495.970 us; speedup 1.0000x reference)
//
#include <hip/hip_runtime.h>
#include <math.h>

#define NN 100000
#define EE 1600000
#define F0 166
#define HID 76
#define H3 228
#define CHID 510
#define SLOPE 0.22916666666666666f
#define CAND_MAX 4096

__device__ __forceinline__ unsigned f2key(float f){
    unsigned u = __float_as_uint(f);
    return (u & 0x80000000u) ? ~u : (u | 0x80000000u);
}
__device__ __forceinline__ float key2f(unsigned k){
    unsigned u = (k & 0x80000000u) ? (k & 0x7fffffffu) : ~k;
    return __uint_as_float(u);
}

// ---- scorer norms: invn[i] = 1/||scorer_i|| ----
__global__ void scorer_norms_k(const float* __restrict__ s0, const float* __restrict__ s1,
                               float* __restrict__ outn){
    __shared__ float red[256];
    int tid = threadIdx.x;
    float a = 0.f;
    for (int k = tid; k < F0; k += 256) a += s0[k]*s0[k];
    red[tid] = a; __syncthreads();
    for (int s = 128; s > 0; s >>= 1){ if (tid < s) red[tid] += red[tid+s]; __syncthreads(); }
    if (tid == 0) outn[0] = 1.0f/sqrtf(red[0]);
    __syncthreads();
    float b = 0.f;
    for (int k = tid; k < HID; k += 256) b += s1[k]*s1[k];
    red[tid] = b; __syncthreads();
    for (int s = 128; s > 0; s >>= 1){ if (tid < s) red[tid] += red[tid+s]; __syncthreads(); }
    if (tid == 0) outn[1] = 1.0f/sqrtf(red[0]);
}

// ---- transpose mlp_w1 (76x510 -> 510x76) ----
__global__ void transpose_w1_k(const float* __restrict__ w1, float* __restrict__ w1t){
    int idx = blockIdx.x*256 + threadIdx.x;
    if (idx < CHID*HID){
        int j = idx / HID, k = idx % HID;
        w1t[idx] = w1[k*CHID + j];
    }
}

// ---- degree count ----
__global__ void deg_k(const int* __restrict__ src, const int* __restrict__ dst,
                      int* degO, int* degI){
    int e = blockIdx.x*256 + threadIdx.x;
    if (e < EE){
        atomicAdd(&degO[src[e]], 1);
        atomicAdd(&degI[dst[e]], 1);
    }
}

__global__ void norm_k(const int* __restrict__ degO, const int* __restrict__ degI,
                       float* __restrict__ nO, float* __restrict__ nI){
    int n = blockIdx.x*256 + threadIdx.x;
    if (n < NN){
        int o = degO[n]; if (o < 1) o = 1;
        int i = degI[n]; if (i < 1) i = 1;
        nO[n] = 1.0f/sqrtf((float)o);
        nI[n] = 1.0f/sqrtf((float)i);
    }
}

// ---- hierarchical exclusive scan of deg_in -> row_start ----
__global__ __launch_bounds__(1024) void scan_block_k(const int* __restrict__ deg,
                                                     int* __restrict__ rs, int* __restrict__ sums){
    __shared__ int sd[1024];
    int tid = threadIdx.x;
    int gid = blockIdx.x*1024 + tid;
    int v = (gid < NN) ? deg[gid] : 0;
    sd[tid] = v; __syncthreads();
    for (int off = 1; off < 1024; off <<= 1){
        int t = (tid >= off) ? sd[tid - off] : 0;
        __syncthreads();
        sd[tid] += t;
        __syncthreads();
    }
    if (gid < NN) rs[gid] = sd[tid] - v;
    if (tid == 1023) sums[blockIdx.x] = sd[tid];
}

__global__ void scan_sums_k(int* sums){
    if (threadIdx.x == 0){
        int acc = 0;
        for (int b = 0; b < 98; b++){ int v = sums[b]; sums[b] = acc; acc += v; }
    }
}

__global__ __launch_bounds__(1024) void add_off_k(int* __restrict__ rs, const int* __restrict__ sums){
    int gid = blockIdx.x*1024 + threadIdx.x;
    if (gid < NN) rs[gid] += sums[blockIdx.x];
}

// ---- CSR fill (bucket by dst, col = src) ----
__global__ void fill_k(const int* __restrict__ src, const int* __restrict__ dst,
                       const int* __restrict__ rs, int* fc, int* __restrict__ col){
    int e = blockIdx.x*256 + threadIdx.x;
    if (e < EE){
        int d = dst[e];
        int p = rs[d] + atomicAdd(&fc[d], 1);
        col[p] = src[e];
    }
}

// ---- scores + 16-bit-prefix histogram ----
template<int F>
__global__ void score_hist_k(const float* __restrict__ x, const float* __restrict__ scorer,
                             const float* __restrict__ invn, float* __restrict__ scores,
                             unsigned* hist){
    int n = blockIdx.x*256 + threadIdx.x;
    if (n >= NN) return;
    const float* xr = x + (size_t)n*F;
    float s = 0.f;
    for (int k = 0; k < F; k++) s += xr[k]*scorer[k];
    s *= invn[0];
    scores[n] = s;
    atomicAdd(&hist[f2key(s) >> 16], 1u);
}

// ---- find threshold bin such that count(bin >= thr) >= 76 ----
__global__ void select_bin_k(const unsigned* __restrict__ hist, int* thr){
    __shared__ unsigned cs[256];
    int tid = threadIdx.x;
    unsigned s = 0;
    int base = 65535 - tid*256;
    for (int j = 0; j < 256; j++) s += hist[base - j];
    cs[tid] = s; __syncthreads();
    if (tid == 0){
        unsigned acc = 0; int c = 0;
        for (; c < 256; c++){ if (acc + cs[c] >= 76u) break; acc += cs[c]; }
        int b = 65535 - c*256;
        int sel = 0;
        for (int j = 0; j < 256; j++){
            acc += hist[b - j];
            if (acc >= 76u){ sel = b - j; break; }
        }
        *thr = sel;
    }
}

__global__ void compact_k(const float* __restrict__ scores, const int* __restrict__ thr,
                          float* __restrict__ cv, int* __restrict__ ci, int* cnt){
    int n = blockIdx.x*256 + threadIdx.x;
    if (n >= NN) return;
    float s = scores[n];
    if ((int)(f2key(s) >> 16) >= *thr){
        int p = atomicAdd(cnt, 1);
        if (p < CAND_MAX){ cv[p] = s; ci[p] = n; }
    }
}

// ---- exact top-76 (value desc, index asc), single wave ----
__global__ void topk_k(const float* __restrict__ cv, const int* __restrict__ ci,
                       const int* __restrict__ cnt, int* __restrict__ topidx,
                       float* __restrict__ tanhv){
    __shared__ unsigned long long keys[CAND_MAX];
    int tid = threadIdx.x;
    int M = *cnt; if (M > CAND_MAX) M = CAND_MAX;
    for (int i = tid; i < M; i += 64)
        keys[i] = ((unsigned long long)f2key(cv[i]) << 32) | (unsigned)(~ci[i]);
    __syncthreads();
    for (int j = 0; j < 76; j++){
        unsigned long long b = 0;
        for (int i = tid; i < M; i += 64){
            unsigned long long k = keys[i];
            if (k > b) b = k;
        }
        #pragma unroll
        for (int off = 32; off > 0; off >>= 1){
            unsigned long long o = __shfl_down(b, off, 64);
            if (o > b) b = o;
        }
        b = __shfl(b, 0, 64);
        if (tid == 0){
            unsigned idx = ~(unsigned)(b & 0xffffffffu);
            float v = key2f((unsigned)(b >> 32));
            topidx[j] = (int)idx;
            tanhv[j]  = tanhf(v);
        }
        for (int i = tid; i < M; i += 64) if (keys[i] == b) keys[i] = 0ull;
        __syncthreads();
    }
}

// ---- GRU weight evolution, one block per matrix row, in-place ----
template<int F>
__global__ void gru_k(const float* __restrict__ cur, const int* __restrict__ topidx,
                      const float* __restrict__ tanhv, float* __restrict__ W,
                      const float* __restrict__ wih, const float* __restrict__ whh,
                      const float* __restrict__ bih, const float* __restrict__ bhh){
    __shared__ float xr[HID], hr[HID], gx[H3], gh[H3];
    int r = blockIdx.x, tid = threadIdx.x;
    if (tid < HID){
        xr[tid] = cur[(size_t)topidx[tid]*F + r] * tanhv[tid];
        hr[tid] = W[r*HID + tid];
    }
    __syncthreads();
    if (tid < H3){
        const float* wi = wih + tid*HID;
        const float* wh = whh + tid*HID;
        float sa = 0.f, sb = 0.f;
        for (int k = 0; k < HID; k++){ sa += xr[k]*wi[k]; sb += hr[k]*wh[k]; }
        gx[tid] = bih[tid] + sa;
        gh[tid] = bhh[tid] + sb;
    }
    __syncthreads();
    if (tid < HID){
        float rr = 1.f/(1.f + expf(-(gx[tid] + gh[tid])));
        float zz = 1.f/(1.f + expf(-(gx[HID+tid] + gh[HID+tid])));
        float nn = tanhf(gx[2*HID+tid] + rr*gh[2*HID+tid]);
        W[r*HID + tid] = (1.f - zz)*nn + zz*hr[tid];
    }
}

// ---- h = (x @ W) * norm_out  (thread per node, uniform W -> s_load) ----
template<int F>
__global__ void gemm_k(const float* __restrict__ x, const float* __restrict__ W,
                       const float* __restrict__ nO, float* __restrict__ h){
    int n = blockIdx.x*256 + threadIdx.x;
    if (n >= NN) return;
    const float* xr = x + (size_t)n*F;
    const float4* W4 = (const float4*)W;
    float4 acc[19];
    #pragma unroll
    for (int j = 0; j < 19; j++) acc[j] = make_float4(0.f,0.f,0.f,0.f);
    for (int k = 0; k < F; k++){
        float xk = xr[k];
        #pragma unroll
        for (int j = 0; j < 19; j++){
            float4 w = W4[k*19 + j];
            acc[j].x += xk*w.x; acc[j].y += xk*w.y;
            acc[j].z += xk*w.z; acc[j].w += xk*w.w;
        }
    }
    float nm = nO[n];
    float4* h4 = (float4*)h + (size_t)n*19;
    #pragma unroll
    for (int j = 0; j < 19; j++){
        float4 a = acc[j];
        h4[j] = make_float4(a.x*nm, a.y*nm, a.z*nm, a.w*nm);
    }
}

// ---- CSR aggregation + dst-norm + leaky, thread per (node, float4 chunk) ----
__global__ void agg_k(const int* __restrict__ rs, const int* __restrict__ degI,
                      const int* __restrict__ col, const float* __restrict__ h,
                      const float* __restrict__ nI, float* __restrict__ ft){
    int idx = blockIdx.x*256 + threadIdx.x;
    if (idx >= NN*19) return;
    int n = idx/19, c = idx%19;
    int st = rs[n], cnt = degI[n];
    const float4* h4 = (const float4*)h;
    float ax=0.f, ay=0.f, az=0.f, aw=0.f;
    for (int e = 0; e < cnt; e++){
        int s = col[st + e];
        float4 v = h4[(size_t)s*19 + c];
        ax += v.x; ay += v.y; az += v.z; aw += v.w;
    }
    float nm = nI[n];
    ax*=nm; ay*=nm; az*=nm; aw*=nm;
    ax = ax >= 0.f ? ax : ax*SLOPE;
    ay = ay >= 0.f ? ay : ay*SLOPE;
    az = az >= 0.f ? az : az*SLOPE;
    aw = aw >= 0.f ? aw : aw*SLOPE;
    ((float4*)ft)[(size_t)n*19 + c] = make_float4(ax,ay,az,aw);
}

// ---- fused classifier MLP ----
__global__ void mlp_k(const float* __restrict__ ft, const float* __restrict__ w1t,
                      const float* __restrict__ b1, const float* __restrict__ w2,
                      const float* __restrict__ b2, float* __restrict__ out){
    int n = blockIdx.x*256 + threadIdx.x;
    if (n >= NN) return;
    const float4* hr4 = (const float4*)ft + (size_t)n*19;
    float4 h[19];
    #pragma unroll
    for (int k = 0; k < 19; k++) h[k] = hr4[k];
    float a0 = b2[0], a1 = b2[1];
    for (int j = 0; j < CHID; j++){
        const float4* wr = (const float4*)(w1t + j*HID);
        float s = b1[j];
        #pragma unroll
        for (int k = 0; k < 19; k++){
            float4 w = wr[k];
            s += h[k].x*w.x + h[k].y*w.y + h[k].z*w.z + h[k].w*w.w;
        }
        s = fmaxf(s, 0.f);
        a0 += s*w2[j*2];
        a1 += s*w2[j*2+1];
    }
    out[(size_t)n*2]   = a0;
    out[(size_t)n*2+1] = a1;
}

extern "C" void kernel_launch(void* const* d_in, const int* in_sizes, int n_in,
                              void* d_out, int out_size, void* d_ws, size_t ws_size,
                              hipStream_t stream)
{
    (void)in_sizes; (void)n_in; (void)out_size; (void)ws_size;
    const float* feats   = (const float*)d_in[0];
    const int*   src     = (const int*)d_in[1];
    const int*   dst     = (const int*)d_in[2];
    const float* scorer0 = (const float*)d_in[3];
    const float* scorer1 = (const float*)d_in[4];
    const float* gcnw[2] = {(const float*)d_in[5],  (const float*)d_in[6]};
    const float* wih[2]  = {(const float*)d_in[7],  (const float*)d_in[11]};
    const float* whh[2]  = {(const float*)d_in[8],  (const float*)d_in[12]};
    const float* bih[2]  = {(const float*)d_in[9],  (const float*)d_in[13]};
    const float* bhh[2]  = {(const float*)d_in[10], (const float*)d_in[14]};
    const float* w1 = (const float*)d_in[15];
    const float* b1 = (const float*)d_in[16];
    const float* w2 = (const float*)d_in[17];
    const float* b2 = (const float*)d_in[18];
    float* out = (float*)d_out;

    char* p = (char*)d_ws;
    auto alloc = [&](size_t bytes) -> void* {
        void* r = (void*)p;
        p += (bytes + 255) & ~(size_t)255;
        return r;
    };
    float* ft[3];
    for (int t = 0; t < 3; t++) ft[t] = (float*)alloc((size_t)NN*HID*4);
    float* hbuf = (float*)alloc((size_t)NN*HID*4);
    int*   col  = (int*)alloc((size_t)EE*4);
    float *nO[3], *nI[3]; int *rs[3], *dI[3];
    for (int t = 0; t < 3; t++){
        nO[t] = (float*)alloc((size_t)NN*4);
        nI[t] = (float*)alloc((size_t)NN*4);
        rs[t] = (int*)alloc((size_t)NN*4);
        dI[t] = (int*)alloc((size_t)NN*4);
    }
    int*      dO     = (int*)alloc((size_t)NN*4);
    int*      fc     = (int*)alloc((size_t)NN*4);
    float*    scores = (float*)alloc((size_t)NN*4);
    unsigned* hist   = (unsigned*)alloc(65536*4);
    float*    cv     = (float*)alloc(CAND_MAX*4);
    int*      ci     = (int*)alloc(CAND_MAX*4);
    int*      ccnt   = (int*)alloc(256);
    int*      thr    = (int*)alloc(256);
    int*      topidx = (int*)alloc(128*4);
    float*    tanhv  = (float*)alloc(128*4);
    float*    Wbuf   = (float*)alloc((size_t)F0*HID*4);
    float*    invn   = (float*)alloc(256);
    int*      sums   = (int*)alloc(128*4);
    float*    w1t    = (float*)alloc((size_t)CHID*HID*4);

    const int gN = (NN + 255)/256;
    const int gE = (EE + 255)/256;
    const int gS = 98;
    const int gA = (NN*19 + 255)/256;
    const int gT = (CHID*HID + 255)/256;

    scorer_norms_k<<<1,256,0,stream>>>(scorer0, scorer1, invn);
    transpose_w1_k<<<gT,256,0,stream>>>(w1, w1t);

    for (int t = 0; t < 3; t++){
        hipMemsetAsync(dO, 0, (size_t)NN*4, stream);
        hipMemsetAsync(dI[t], 0, (size_t)NN*4, stream);
        deg_k<<<gE,256,0,stream>>>(src + (size_t)t*EE, dst + (size_t)t*EE, dO, dI[t]);
        norm_k<<<gN,256,0,stream>>>(dO, dI[t], nO[t], nI[t]);
        scan_block_k<<<gS,1024,0,stream>>>(dI[t], rs[t], sums);
        scan_sums_k<<<1,64,0,stream>>>(sums);
        add_off_k<<<gS,1024,0,stream>>>(rs[t], sums);
    }

    for (int i = 0; i < 2; i++){
        int F = (i == 0) ? F0 : HID;
        hipMemcpyAsync(Wbuf, gcnw[i], (size_t)F*HID*4, hipMemcpyDeviceToDevice, stream);
        for (int t = 0; t < 3; t++){
            const float* cur = (i == 0) ? (feats + (size_t)t*NN*F0) : ft[t];
            hipMemsetAsync(fc, 0, (size_t)NN*4, stream);
            fill_k<<<gE,256,0,stream>>>(src + (size_t)t*EE, dst + (size_t)t*EE, rs[t], fc, col);
            hipMemsetAsync(hist, 0, 65536*4, stream);
            hipMemsetAsync(ccnt, 0, 4, stream);
            if (i == 0) score_hist_k<F0><<<gN,256,0,stream>>>(cur, scorer0, invn+0, scores, hist);
            else        score_hist_k<HID><<<gN,256,0,stream>>>(cur, scorer1, invn+1, scores, hist);
            select_bin_k<<<1,256,0,stream>>>(hist, thr);
            compact_k<<<gN,256,0,stream>>>(scores, thr, cv, ci, ccnt);
            topk_k<<<1,64,0,stream>>>(cv, ci, ccnt, topidx, tanhv);
            if (i == 0){
                gru_k<F0><<<F0,256,0,stream>>>(cur, topidx, tanhv, Wbuf, wih[i], whh[i], bih[i], bhh[i]);
                gemm_k<F0><<<gN,256,0,stream>>>(cur, Wbuf, nO[t], hbuf);
            } else {
                gru_k<HID><<<HID,256,0,stream>>>(cur, topidx, tanhv, Wbuf, wih[i], whh[i], bih[i], bhh[i]);
                gemm_k<HID><<<gN,256,0,stream>>>(cur, Wbuf, nO[t], hbuf);
            }
            agg_k<<<gA,256,0,stream>>>(rs[t], dI[t], col, hbuf, nI[t], ft[t]);
        }
    }

    mlp_k<<<gN,256,0,stream>>>(ft[2], w1t, b1, w2, b2, out);
}